// Round 1
// baseline (1456.249 us; speedup 1.0000x reference)
//
#include <hip/hip_runtime.h>
#include <stdint.h>

#define EE 8
#define TT 1024
#define DD 2048
#define HH 4096

typedef unsigned short u16;
using s16x8 = __attribute__((ext_vector_type(8))) short;
using f32x4 = __attribute__((ext_vector_type(4))) float;

#define AS1 __attribute__((address_space(1)))
#define AS3 __attribute__((address_space(3)))

__device__ __forceinline__ uint32_t pack_bf16(float lo, float hi) {
#if __has_builtin(__builtin_amdgcn_cvt_pk_bf16_f32)
  typedef __bf16 bf16x2 __attribute__((ext_vector_type(2)));
  bf16x2 r = __builtin_amdgcn_cvt_pk_bf16_f32(lo, hi);
  return __builtin_bit_cast(uint32_t, r);
#else
  uint32_t ulo = __builtin_bit_cast(uint32_t, lo);
  uint32_t uhi = __builtin_bit_cast(uint32_t, hi);
  ulo += 0x7fffu + ((ulo >> 16) & 1u);
  uhi += 0x7fffu + ((uhi >> 16) & 1u);
  return (ulo >> 16) | (uhi & 0xffff0000u);
#endif
}

__device__ __forceinline__ u16 bf16_bits(float v) {
  uint32_t u = __builtin_bit_cast(uint32_t, v);
  u += 0x7fffu + ((u >> 16) & 1u);
  return (u16)(u >> 16);
}

// ---------------------------------------------------------------------------
// Prepass A: straight fp32 -> bf16 convert (x, w3, w2). Grid-stride float4.
// ---------------------------------------------------------------------------
__global__ __launch_bounds__(256)
void k_cvt(const float* __restrict__ in, u16* __restrict__ out, int n4) {
  int i = blockIdx.x * blockDim.x + threadIdx.x;
  const int stride = gridDim.x * blockDim.x;
  for (; i < n4; i += stride) {
    float4 v = ((const float4*)in)[i];
    uint2 o;
    o.x = pack_bf16(v.x, v.y);
    o.y = pack_bf16(v.z, v.w);
    ((uint2*)out)[i] = o;
  }
}

// ---------------------------------------------------------------------------
// Prepass B: w1 [E][D][H] fp32 -> w1t [E][H][D] bf16 (transpose-convert).
// 64x64 tile through LDS; both global sides coalesced (float4 in, uint2 out).
// ---------------------------------------------------------------------------
__global__ __launch_bounds__(256)
void k_tr(const float* __restrict__ in, u16* __restrict__ out) {
  const int e  = blockIdx.z;
  const int d0 = blockIdx.y * 64;
  const int h0 = blockIdx.x * 64;
  __shared__ u16 sT[64][68];   // pad 4 u16 -> row stride 136 B (8B aligned, conflict-spread)
  const int r  = threadIdx.x >> 4;         // 0..15
  const int c4 = (threadIdx.x & 15) * 4;   // 0,4,..,60
  #pragma unroll
  for (int p = 0; p < 4; ++p) {
    int d = r + p * 16;
    float4 v = *(const float4*)(in + ((size_t)e * DD + d0 + d) * HH + h0 + c4);
    uint2 o;
    o.x = pack_bf16(v.x, v.y);
    o.y = pack_bf16(v.z, v.w);
    *(uint2*)&sT[d][c4] = o;
  }
  __syncthreads();
  #pragma unroll
  for (int p = 0; p < 4; ++p) {
    int h = r + p * 16;
    uint2 o;
    o.x = (uint32_t)sT[c4 + 0][h] | ((uint32_t)sT[c4 + 1][h] << 16);
    o.y = (uint32_t)sT[c4 + 2][h] | ((uint32_t)sT[c4 + 3][h] << 16);
    *(uint2*)(out + ((size_t)e * HH + h0 + h) * DD + d0 + c4) = o;
  }
}

// ---------------------------------------------------------------------------
// Kernel 1 (bf16 fast path): h = silu(x@w1) * (x@w3^T).
// All operands bf16 in ws; all 3 tiles staged via global_load_lds width-16
// into unpadded [128][32], double-buffered, 1 barrier / K-step.
// ---------------------------------------------------------------------------
__global__ __launch_bounds__(256, 2)
void k1_bf16(const u16* __restrict__ xb, const u16* __restrict__ w1t,
             const u16* __restrict__ w3b, u16* __restrict__ hout) {
  const int e  = blockIdx.z;
  const int t0 = blockIdx.y * 128;
  const int h0 = blockIdx.x * 128;
  const int tid  = threadIdx.x;
  const int lane = tid & 63;
  const int wave = tid >> 6;
  const int wm = (wave >> 1) * 64;
  const int wn = (wave & 1) * 64;
  const int l15  = lane & 15;
  const int quad = lane >> 4;

  __shared__ u16 sX[2][128 * 32];
  __shared__ u16 sW1[2][128 * 32];
  __shared__ u16 sW3[2][128 * 32];

  // glds: wave-uniform LDS base + lane*16B; per-lane global source.
  const int gr = lane >> 2;         // row within 16-row chunk
  const int gc = (lane & 3) * 8;    // u16 col within BK=32 (16B chunk)
  const u16* xg  = xb  + ((size_t)(e * TT + t0) + wave * 32 + gr) * DD + gc;
  const u16* w1g = w1t + ((size_t)(e * HH + h0) + wave * 32 + gr) * DD + gc;
  const u16* w3g = w3b + ((size_t)(e * HH + h0) + wave * 32 + gr) * DD + gc;

  f32x4 acc1[4][4], acc3[4][4];
  #pragma unroll
  for (int i = 0; i < 4; ++i)
    #pragma unroll
    for (int j = 0; j < 4; ++j) { acc1[i][j] = (f32x4)0.f; acc3[i][j] = (f32x4)0.f; }

  auto stage = [&](int buf, int ko) {
    const size_t koff = (size_t)ko * 32;
    #pragma unroll
    for (int i = 0; i < 2; ++i) {
      __builtin_amdgcn_global_load_lds(
          (const AS1 uint32_t*)(xg + (size_t)(i * 16) * DD + koff),
          (AS3 uint32_t*)&sX[buf][(wave * 32 + i * 16) * 32], 16, 0, 0);
      __builtin_amdgcn_global_load_lds(
          (const AS1 uint32_t*)(w1g + (size_t)(i * 16) * DD + koff),
          (AS3 uint32_t*)&sW1[buf][(wave * 32 + i * 16) * 32], 16, 0, 0);
      __builtin_amdgcn_global_load_lds(
          (const AS1 uint32_t*)(w3g + (size_t)(i * 16) * DD + koff),
          (AS3 uint32_t*)&sW3[buf][(wave * 32 + i * 16) * 32], 16, 0, 0);
    }
  };

  stage(0, 0);
  __syncthreads();   // vmcnt(0) drain -> buf0 visible

  int cur = 0;
  for (int ko = 0; ko < DD / 32; ++ko) {
    if (ko + 1 < DD / 32) stage(cur ^ 1, ko + 1);  // prefetch stays in flight over MFMA

    s16x8 af[4];
    #pragma unroll
    for (int im = 0; im < 4; ++im)
      af[im] = *(const s16x8*)&sX[cur][(wm + im * 16 + l15) * 32 + quad * 8];
    #pragma unroll
    for (int jn = 0; jn < 4; ++jn) {
      s16x8 b1 = *(const s16x8*)&sW1[cur][(wn + jn * 16 + l15) * 32 + quad * 8];
      s16x8 b3 = *(const s16x8*)&sW3[cur][(wn + jn * 16 + l15) * 32 + quad * 8];
      #pragma unroll
      for (int im = 0; im < 4; ++im) {
        acc1[im][jn] = __builtin_amdgcn_mfma_f32_16x16x32_bf16(af[im], b1, acc1[im][jn], 0, 0, 0);
        acc3[im][jn] = __builtin_amdgcn_mfma_f32_16x16x32_bf16(af[im], b3, acc3[im][jn], 0, 0, 0);
      }
    }
    __syncthreads();
    cur ^= 1;
  }

  #pragma unroll
  for (int im = 0; im < 4; ++im)
    #pragma unroll
    for (int jn = 0; jn < 4; ++jn)
      #pragma unroll
      for (int r = 0; r < 4; ++r) {
        int row = wm + im * 16 + quad * 4 + r;
        int col = wn + jn * 16 + l15;
        float a = acc1[im][jn][r];
        float g = acc3[im][jn][r];
        float s = 1.0f / (1.0f + __expf(-a));
        hout[(size_t)(e * TT + t0 + row) * HH + h0 + col] = bf16_bits(a * s * g);
      }
}

// ---------------------------------------------------------------------------
// Kernel 2 (bf16 fast path): out = h @ w2^T, both operands bf16 via glds.
// ---------------------------------------------------------------------------
__global__ __launch_bounds__(256, 3)
void k2_bf16(const u16* __restrict__ hin, const u16* __restrict__ w2b,
             float* __restrict__ out) {
  const int e  = blockIdx.z;
  const int t0 = blockIdx.y * 128;
  const int d0 = blockIdx.x * 128;
  const int tid  = threadIdx.x;
  const int lane = tid & 63;
  const int wave = tid >> 6;
  const int wm = (wave >> 1) * 64;
  const int wn = (wave & 1) * 64;
  const int l15  = lane & 15;
  const int quad = lane >> 4;

  __shared__ u16 sA[2][128 * 32];
  __shared__ u16 sB[2][128 * 32];

  const int gr = lane >> 2;
  const int gc = (lane & 3) * 8;
  const u16* ag = hin + ((size_t)(e * TT + t0) + wave * 32 + gr) * HH + gc;
  const u16* bg = w2b + ((size_t)(e * DD + d0) + wave * 32 + gr) * HH + gc;

  f32x4 acc[4][4];
  #pragma unroll
  for (int i = 0; i < 4; ++i)
    #pragma unroll
    for (int j = 0; j < 4; ++j) acc[i][j] = (f32x4)0.f;

  auto stage = [&](int buf, int ko) {
    const size_t koff = (size_t)ko * 32;
    #pragma unroll
    for (int i = 0; i < 2; ++i) {
      __builtin_amdgcn_global_load_lds(
          (const AS1 uint32_t*)(ag + (size_t)(i * 16) * HH + koff),
          (AS3 uint32_t*)&sA[buf][(wave * 32 + i * 16) * 32], 16, 0, 0);
      __builtin_amdgcn_global_load_lds(
          (const AS1 uint32_t*)(bg + (size_t)(i * 16) * HH + koff),
          (AS3 uint32_t*)&sB[buf][(wave * 32 + i * 16) * 32], 16, 0, 0);
    }
  };

  stage(0, 0);
  __syncthreads();

  int cur = 0;
  for (int ko = 0; ko < HH / 32; ++ko) {
    if (ko + 1 < HH / 32) stage(cur ^ 1, ko + 1);

    s16x8 af[4];
    #pragma unroll
    for (int im = 0; im < 4; ++im)
      af[im] = *(const s16x8*)&sA[cur][(wm + im * 16 + l15) * 32 + quad * 8];
    #pragma unroll
    for (int jn = 0; jn < 4; ++jn) {
      s16x8 bf = *(const s16x8*)&sB[cur][(wn + jn * 16 + l15) * 32 + quad * 8];
      #pragma unroll
      for (int im = 0; im < 4; ++im)
        acc[im][jn] = __builtin_amdgcn_mfma_f32_16x16x32_bf16(af[im], bf, acc[im][jn], 0, 0, 0);
    }
    __syncthreads();
    cur ^= 1;
  }

  #pragma unroll
  for (int im = 0; im < 4; ++im)
    #pragma unroll
    for (int jn = 0; jn < 4; ++jn)
      #pragma unroll
      for (int r = 0; r < 4; ++r) {
        int row = wm + im * 16 + quad * 4 + r;
        int col = wn + jn * 16 + l15;
        out[(size_t)(e * TT + t0 + row) * DD + d0 + col] = acc[im][jn][r];
      }
}

// ---------------------------------------------------------------------------
// Fallback path (ws too small): previous harness-verified fp32-staging kernels.
// ---------------------------------------------------------------------------
__global__ __launch_bounds__(256, 2)
void k1_upgate(const float* __restrict__ x, const float* __restrict__ w1,
               const float* __restrict__ w3, u16* __restrict__ hout) {
  const int e  = blockIdx.z;
  const int t0 = blockIdx.y * 128;
  const int h0 = blockIdx.x * 128;
  const int tid = threadIdx.x;
  const int lane = tid & 63;
  const int wave = tid >> 6;
  const int wm = (wave >> 1) * 64;
  const int wn = (wave & 1) * 64;
  const int l15 = lane & 15;
  const int quad = lane >> 4;

  __shared__ u16 sX [128 * 40];
  __shared__ u16 sW1[128 * 40];
  __shared__ u16 sW3[128 * 40];

  const int sr = tid >> 3;
  const int sc = tid & 7;
  const int k2 = tid >> 4;
  const int ns = tid & 15;

  const float* xg  = x  + (size_t)(e * TT + t0 + sr) * DD + sc * 4;
  const float* w3g = w3 + (size_t)e * HH * DD + (size_t)(h0 + sr) * DD + sc * 4;
  const float* w1g = w1 + (size_t)e * DD * HH + (size_t)(2 * k2) * HH + h0 + ns * 4;

  f32x4 acc1[4][4], acc3[4][4];
  #pragma unroll
  for (int i = 0; i < 4; ++i)
    #pragma unroll
    for (int j = 0; j < 4; ++j) { acc1[i][j] = (f32x4)0.f; acc3[i][j] = (f32x4)0.f; }

  float4 rx[4], rw[4], r0[2], r1[2];

  auto load_tiles = [&](int ko) {
    #pragma unroll
    for (int p = 0; p < 4; ++p) {
      rx[p] = *(const float4*)(xg  + (size_t)p * 32 * DD + (size_t)ko * 32);
      rw[p] = *(const float4*)(w3g + (size_t)p * 32 * DD + (size_t)ko * 32);
    }
    #pragma unroll
    for (int j = 0; j < 2; ++j) {
      r0[j] = *(const float4*)(w1g + (size_t)ko * 32 * HH + j * 64);
      r1[j] = *(const float4*)(w1g + (size_t)ko * 32 * HH + HH + j * 64);
    }
  };

  load_tiles(0);

  for (int ko = 0; ko < DD / 32; ++ko) {
    __syncthreads();
    #pragma unroll
    for (int p = 0; p < 4; ++p) {
      int row = sr + p * 32;
      uint2 vx; vx.x = pack_bf16(rx[p].x, rx[p].y); vx.y = pack_bf16(rx[p].z, rx[p].w);
      uint2 vw; vw.x = pack_bf16(rw[p].x, rw[p].y); vw.y = pack_bf16(rw[p].z, rw[p].w);
      *(uint2*)&sX [row * 40 + sc * 4] = vx;
      *(uint2*)&sW3[row * 40 + sc * 4] = vw;
    }
    #pragma unroll
    for (int j = 0; j < 2; ++j) {
      int nb = ns * 4 + j * 64;
      *(uint32_t*)&sW1[(nb + 0) * 40 + 2 * k2] = pack_bf16(r0[j].x, r1[j].x);
      *(uint32_t*)&sW1[(nb + 1) * 40 + 2 * k2] = pack_bf16(r0[j].y, r1[j].y);
      *(uint32_t*)&sW1[(nb + 2) * 40 + 2 * k2] = pack_bf16(r0[j].z, r1[j].z);
      *(uint32_t*)&sW1[(nb + 3) * 40 + 2 * k2] = pack_bf16(r0[j].w, r1[j].w);
    }
    __syncthreads();
    if (ko + 1 < DD / 32) load_tiles(ko + 1);

    s16x8 af[4];
    #pragma unroll
    for (int im = 0; im < 4; ++im)
      af[im] = *(const s16x8*)&sX[(wm + im * 16 + l15) * 40 + quad * 8];
    #pragma unroll
    for (int jn = 0; jn < 4; ++jn) {
      s16x8 b1 = *(const s16x8*)&sW1[(wn + jn * 16 + l15) * 40 + quad * 8];
      s16x8 b3 = *(const s16x8*)&sW3[(wn + jn * 16 + l15) * 40 + quad * 8];
      #pragma unroll
      for (int im = 0; im < 4; ++im) {
        acc1[im][jn] = __builtin_amdgcn_mfma_f32_16x16x32_bf16(af[im], b1, acc1[im][jn], 0, 0, 0);
        acc3[im][jn] = __builtin_amdgcn_mfma_f32_16x16x32_bf16(af[im], b3, acc3[im][jn], 0, 0, 0);
      }
    }
  }

  #pragma unroll
  for (int im = 0; im < 4; ++im)
    #pragma unroll
    for (int jn = 0; jn < 4; ++jn)
      #pragma unroll
      for (int r = 0; r < 4; ++r) {
        int row = wm + im * 16 + quad * 4 + r;
        int col = wn + jn * 16 + l15;
        float a = acc1[im][jn][r];
        float g = acc3[im][jn][r];
        float s = 1.0f / (1.0f + __expf(-a));
        hout[(size_t)(e * TT + t0 + row) * HH + h0 + col] = bf16_bits(a * s * g);
      }
}

__global__ __launch_bounds__(256, 3)
void k2_down(const u16* __restrict__ hin, const float* __restrict__ w2,
             float* __restrict__ out) {
  const int e  = blockIdx.z;
  const int t0 = blockIdx.y * 128;
  const int d0 = blockIdx.x * 128;
  const int tid = threadIdx.x;
  const int lane = tid & 63;
  const int wave = tid >> 6;
  const int wm = (wave >> 1) * 64;
  const int wn = (wave & 1) * 64;
  const int l15 = lane & 15;
  const int quad = lane >> 4;

  __shared__ u16 sA[128 * 32];
  __shared__ u16 sB[128 * 40];

  const int sr = tid >> 3;
  const int sc = tid & 7;

  const u16*   hg  = hin + (size_t)(e * TT + t0) * HH;
  const float* w2g = w2  + (size_t)e * DD * HH + (size_t)(d0 + sr) * HH + sc * 4;

  const int am = wave * 32 + (lane >> 2);
  const int ak = (lane & 3) * 8;

  f32x4 acc[4][4];
  #pragma unroll
  for (int i = 0; i < 4; ++i)
    #pragma unroll
    for (int j = 0; j < 4; ++j) acc[i][j] = (f32x4)0.f;

  float4 rb[4];
  auto load_b = [&](int ko) {
    #pragma unroll
    for (int p = 0; p < 4; ++p)
      rb[p] = *(const float4*)(w2g + (size_t)p * 32 * HH + (size_t)ko * 32);
  };

  load_b(0);

  for (int ko = 0; ko < HH / 32; ++ko) {
    __syncthreads();
    #pragma unroll
    for (int i = 0; i < 2; ++i) {
      const u16* gp = hg + (size_t)(am + i * 16) * HH + ko * 32 + ak;
      __builtin_amdgcn_global_load_lds((AS1 uint32_t*)gp,
                                       (AS3 uint32_t*)&sA[wave * 1024 + i * 512],
                                       16, 0, 0);
    }
    #pragma unroll
    for (int p = 0; p < 4; ++p) {
      int row = sr + p * 32;
      uint2 vb; vb.x = pack_bf16(rb[p].x, rb[p].y); vb.y = pack_bf16(rb[p].z, rb[p].w);
      *(uint2*)&sB[row * 40 + sc * 4] = vb;
    }
    __syncthreads();
    if (ko + 1 < HH / 32) load_b(ko + 1);

    s16x8 af[4];
    #pragma unroll
    for (int im = 0; im < 4; ++im)
      af[im] = *(const s16x8*)&sA[(wm + im * 16 + l15) * 32 + quad * 8];
    #pragma unroll
    for (int jn = 0; jn < 4; ++jn) {
      s16x8 bf = *(const s16x8*)&sB[(wn + jn * 16 + l15) * 40 + quad * 8];
      #pragma unroll
      for (int im = 0; im < 4; ++im)
        acc[im][jn] = __builtin_amdgcn_mfma_f32_16x16x32_bf16(af[im], bf, acc[im][jn], 0, 0, 0);
    }
  }

  #pragma unroll
  for (int im = 0; im < 4; ++im)
    #pragma unroll
    for (int jn = 0; jn < 4; ++jn)
      #pragma unroll
      for (int r = 0; r < 4; ++r) {
        int row = wm + im * 16 + quad * 4 + r;
        int col = wn + jn * 16 + l15;
        out[(size_t)(e * TT + t0 + row) * DD + d0 + col] = acc[im][jn][r];
      }
}

// ---------------------------------------------------------------------------
// Launch. Workspace layout (fast path, 480 MiB):
//   [0,64M)    h bf16      [64M,96M)   xb bf16
//   [96M,224M) w1t bf16    [224M,352M) w3b bf16   [352M,480M) w2b bf16
// ---------------------------------------------------------------------------
extern "C" void kernel_launch(void* const* d_in, const int* in_sizes, int n_in,
                              void* d_out, int out_size, void* d_ws, size_t ws_size,
                              hipStream_t stream) {
  const float* x  = (const float*)d_in[0];
  const float* w1 = (const float*)d_in[1];
  const float* w2 = (const float*)d_in[2];
  const float* w3 = (const float*)d_in[3];
  float* out = (float*)d_out;

  const size_t SZ_H  = (size_t)EE * TT * HH * 2;   // 64 MiB
  const size_t SZ_XB = (size_t)EE * TT * DD * 2;   // 32 MiB
  const size_t SZ_W  = (size_t)EE * DD * HH * 2;   // 128 MiB
  const size_t OFF_XB  = SZ_H;
  const size_t OFF_W1T = OFF_XB + SZ_XB;
  const size_t OFF_W3B = OFF_W1T + SZ_W;
  const size_t OFF_W2B = OFF_W3B + SZ_W;
  const size_t WS_NEED = OFF_W2B + SZ_W;           // 480 MiB

  u16* hbuf = (u16*)d_ws;

  if (ws_size >= WS_NEED) {
    u16* xb  = (u16*)((char*)d_ws + OFF_XB);
    u16* w1t = (u16*)((char*)d_ws + OFF_W1T);
    u16* w3b = (u16*)((char*)d_ws + OFF_W3B);
    u16* w2b = (u16*)((char*)d_ws + OFF_W2B);

    k_cvt<<<2048, 256, 0, stream>>>(x,  xb,  (int)((size_t)EE * TT * DD / 4));
    k_cvt<<<4096, 256, 0, stream>>>(w3, w3b, (int)((size_t)EE * DD * HH / 4));
    k_cvt<<<4096, 256, 0, stream>>>(w2, w2b, (int)((size_t)EE * DD * HH / 4));
    k_tr <<<dim3(HH / 64, DD / 64, EE), 256, 0, stream>>>(w1, w1t);

    dim3 g1(HH / 128, TT / 128, EE);
    k1_bf16<<<g1, dim3(256), 0, stream>>>(xb, w1t, w3b, hbuf);

    dim3 g2(DD / 128, TT / 128, EE);
    k2_bf16<<<g2, dim3(256), 0, stream>>>(hbuf, w2b, out);
  } else {
    dim3 g1(HH / 128, TT / 128, EE);
    k1_upgate<<<g1, dim3(256), 0, stream>>>(x, w1, w3, hbuf);

    dim3 g2(DD / 128, TT / 128, EE);
    k2_down<<<g2, dim3(256), 0, stream>>>(hbuf, w2, out);
  }
}

// Round 3
// 1399.468 us; speedup vs baseline: 1.0406x; 1.0406x over previous
//
#include <hip/hip_runtime.h>
#include <stdint.h>

#define EE 8
#define TT 1024
#define DD 2048
#define HH 4096

typedef unsigned short u16;
using s16x8 = __attribute__((ext_vector_type(8))) short;
using f32x4 = __attribute__((ext_vector_type(4))) float;

#define AS1 __attribute__((address_space(1)))
#define AS3 __attribute__((address_space(3)))

__device__ __forceinline__ uint32_t pack_bf16(float lo, float hi) {
#if __has_builtin(__builtin_amdgcn_cvt_pk_bf16_f32)
  typedef __bf16 bf16x2 __attribute__((ext_vector_type(2)));
  bf16x2 r = __builtin_amdgcn_cvt_pk_bf16_f32(lo, hi);
  return __builtin_bit_cast(uint32_t, r);
#else
  uint32_t ulo = __builtin_bit_cast(uint32_t, lo);
  uint32_t uhi = __builtin_bit_cast(uint32_t, hi);
  ulo += 0x7fffu + ((ulo >> 16) & 1u);
  uhi += 0x7fffu + ((uhi >> 16) & 1u);
  return (ulo >> 16) | (uhi & 0xffff0000u);
#endif
}

__device__ __forceinline__ u16 bf16_bits(float v) {
  uint32_t u = __builtin_bit_cast(uint32_t, v);
  u += 0x7fffu + ((u >> 16) & 1u);
  return (u16)(u >> 16);
}

// ---------------------------------------------------------------------------
// Prepass A: straight fp32 -> bf16 convert (x, w3). Grid-stride float4.
// ---------------------------------------------------------------------------
__global__ __launch_bounds__(256)
void k_cvt(const float* __restrict__ in, u16* __restrict__ out, int n4) {
  int i = blockIdx.x * blockDim.x + threadIdx.x;
  const int stride = gridDim.x * blockDim.x;
  for (; i < n4; i += stride) {
    float4 v = ((const float4*)in)[i];
    uint2 o;
    o.x = pack_bf16(v.x, v.y);
    o.y = pack_bf16(v.z, v.w);
    ((uint2*)out)[i] = o;
  }
}

// ---------------------------------------------------------------------------
// Prepass B: w1 [E][D][H] fp32 -> w1t [E][H][D] bf16 (transpose-convert).
// ---------------------------------------------------------------------------
__global__ __launch_bounds__(256)
void k_tr(const float* __restrict__ in, u16* __restrict__ out) {
  const int e  = blockIdx.z;
  const int d0 = blockIdx.y * 64;
  const int h0 = blockIdx.x * 64;
  __shared__ u16 sT[64][68];
  const int r  = threadIdx.x >> 4;         // 0..15
  const int c4 = (threadIdx.x & 15) * 4;   // 0,4,..,60
  #pragma unroll
  for (int p = 0; p < 4; ++p) {
    int d = r + p * 16;
    float4 v = *(const float4*)(in + ((size_t)e * DD + d0 + d) * HH + h0 + c4);
    uint2 o;
    o.x = pack_bf16(v.x, v.y);
    o.y = pack_bf16(v.z, v.w);
    *(uint2*)&sT[d][c4] = o;
  }
  __syncthreads();
  #pragma unroll
  for (int p = 0; p < 4; ++p) {
    int h = r + p * 16;
    uint2 o;
    o.x = (uint32_t)sT[c4 + 0][h] | ((uint32_t)sT[c4 + 1][h] << 16);
    o.y = (uint32_t)sT[c4 + 2][h] | ((uint32_t)sT[c4 + 3][h] << 16);
    *(uint2*)(out + ((size_t)e * HH + h0 + h) * DD + d0 + c4) = o;
  }
}

// ---------------------------------------------------------------------------
// Kernel 1: h = silu(x@w1) * (x@w3^T), all-bf16 operands.
// 3-buffer counted-vmcnt pipeline (T4): one s_barrier per K-step, vmcnt(6)
// keeps 6 glds (next tile's stage) in flight across the barrier.
// XOR-swizzled LDS (T2): glds source pre-permuted per-lane, read slot
// quad ^ ((l15>>1)&3) -> 2-way bank aliasing (free).
// Extra grid-z slab (z==EE) converts w2 fp32->bf16 concurrently (BW overlap).
// ---------------------------------------------------------------------------
__global__ __launch_bounds__(256, 2)
void k1_bf16(const u16* __restrict__ xb, const u16* __restrict__ w1t,
             const u16* __restrict__ w3b, u16* __restrict__ hout,
             const float* __restrict__ w2, u16* __restrict__ w2b) {
  // ---- fused w2 conversion blocks (overlap with GEMM blocks) ----
  if (blockIdx.z == EE) {
    const int nb = gridDim.x * gridDim.y;
    const int bidx = blockIdx.y * gridDim.x + blockIdx.x;
    int i = bidx * blockDim.x + threadIdx.x;
    const int stride = nb * blockDim.x;
    const int n4 = (int)((size_t)EE * DD * HH / 4);
    for (; i < n4; i += stride) {
      float4 v = ((const float4*)w2)[i];
      uint2 o;
      o.x = pack_bf16(v.x, v.y);
      o.y = pack_bf16(v.z, v.w);
      ((uint2*)w2b)[i] = o;
    }
    return;
  }

  const int e  = blockIdx.z;
  const int t0 = blockIdx.y * 128;
  const int h0 = blockIdx.x * 128;
  const int tid  = threadIdx.x;
  const int lane = tid & 63;
  const int wave = tid >> 6;
  const int wm = (wave >> 1) * 64;
  const int wn = (wave & 1) * 64;
  const int l15  = lane & 15;
  const int quad = lane >> 4;

  __shared__ u16 sX [3][128 * 32];
  __shared__ u16 sW1[3][128 * 32];
  __shared__ u16 sW3[3][128 * 32];

  // glds: dest = wave-uniform base + lane*16B -> (row = lane>>2, slot = lane&3).
  // Source pre-swizzled: chunk = (lane&3) ^ ((lane>>3)&3)  [= slot ^ ((row>>1)&3)]
  const int gr  = lane >> 2;
  const int gsw = (((lane & 3) ^ ((lane >> 3) & 3))) * 8;  // u16 col
  const u16* xg  = xb  + ((size_t)(e * TT + t0) + wave * 32 + gr) * DD + gsw;
  const u16* w1g = w1t + ((size_t)(e * HH + h0) + wave * 32 + gr) * DD + gsw;
  const u16* w3g = w3b + ((size_t)(e * HH + h0) + wave * 32 + gr) * DD + gsw;

  // read-side swizzle: slot' = quad ^ ((l15>>1)&3), per-lane constant
  const int rsw = (quad ^ ((l15 >> 1) & 3)) * 8;

  f32x4 acc1[4][4], acc3[4][4];
  #pragma unroll
  for (int i = 0; i < 4; ++i)
    #pragma unroll
    for (int j = 0; j < 4; ++j) { acc1[i][j] = (f32x4)0.f; acc3[i][j] = (f32x4)0.f; }

  auto stage = [&](int buf, int ko) {
    const size_t koff = (size_t)ko * 32;
    #pragma unroll
    for (int i = 0; i < 2; ++i) {
      __builtin_amdgcn_global_load_lds(
          (const AS1 uint32_t*)(xg + (size_t)(i * 16) * DD + koff),
          (AS3 uint32_t*)&sX[buf][(wave * 32 + i * 16) * 32], 16, 0, 0);
      __builtin_amdgcn_global_load_lds(
          (const AS1 uint32_t*)(w1g + (size_t)(i * 16) * DD + koff),
          (AS3 uint32_t*)&sW1[buf][(wave * 32 + i * 16) * 32], 16, 0, 0);
      __builtin_amdgcn_global_load_lds(
          (const AS1 uint32_t*)(w3g + (size_t)(i * 16) * DD + koff),
          (AS3 uint32_t*)&sW3[buf][(wave * 32 + i * 16) * 32], 16, 0, 0);
    }
  };

  const int NT = DD / 32;   // 64
  stage(0, 0);
  stage(1, 1);

  int cur = 0;
  for (int t = 0; t < NT; ++t) {
    // tile t ready once OWN stage(t) is drained (vmcnt<=6 leaves only stage(t+1))
    // + barrier => whole block's tile t is in LDS, and all waves finished
    // reading tile t-1 (so slot (t+2)%3 == (t-1)%3 is safe to overwrite).
    __builtin_amdgcn_sched_barrier(0);
    asm volatile("s_waitcnt vmcnt(6)" ::: "memory");
    __builtin_amdgcn_s_barrier();
    __builtin_amdgcn_sched_barrier(0);

    int nslot = cur + 2; if (nslot >= 3) nslot -= 3;
    stage(nslot, (t + 2) & (NT - 1));   // dummy re-stage at tail keeps vmcnt exact
    __builtin_amdgcn_sched_barrier(0);

    s16x8 af[4];
    #pragma unroll
    for (int im = 0; im < 4; ++im)
      af[im] = *(const s16x8*)&sX[cur][(wm + im * 16 + l15) * 32 + rsw];
    #pragma unroll
    for (int jn = 0; jn < 4; ++jn) {
      s16x8 b1 = *(const s16x8*)&sW1[cur][(wn + jn * 16 + l15) * 32 + rsw];
      s16x8 b3 = *(const s16x8*)&sW3[cur][(wn + jn * 16 + l15) * 32 + rsw];
      #pragma unroll
      for (int im = 0; im < 4; ++im) {
        acc1[im][jn] = __builtin_amdgcn_mfma_f32_16x16x32_bf16(af[im], b1, acc1[im][jn], 0, 0, 0);
        acc3[im][jn] = __builtin_amdgcn_mfma_f32_16x16x32_bf16(af[im], b3, acc3[im][jn], 0, 0, 0);
      }
    }
    ++cur; if (cur >= 3) cur -= 3;
  }
  // drain dangling prefetches before LDS may be deallocated
  asm volatile("s_waitcnt vmcnt(0)" ::: "memory");

  #pragma unroll
  for (int im = 0; im < 4; ++im)
    #pragma unroll
    for (int jn = 0; jn < 4; ++jn)
      #pragma unroll
      for (int r = 0; r < 4; ++r) {
        int row = wm + im * 16 + quad * 4 + r;
        int col = wn + jn * 16 + l15;
        float a = acc1[im][jn][r];
        float g = acc3[im][jn][r];
        float s = 1.0f / (1.0f + __expf(-a));
        hout[(size_t)(e * TT + t0 + row) * HH + h0 + col] = bf16_bits(a * s * g);
      }
}

// ---------------------------------------------------------------------------
// Kernel 2: out = h @ w2^T, same 3-buffer counted pipeline + swizzle.
// ---------------------------------------------------------------------------
__global__ __launch_bounds__(256, 3)
void k2_bf16(const u16* __restrict__ hin, const u16* __restrict__ w2b,
             float* __restrict__ out) {
  const int e  = blockIdx.z;
  const int t0 = blockIdx.y * 128;
  const int d0 = blockIdx.x * 128;
  const int tid  = threadIdx.x;
  const int lane = tid & 63;
  const int wave = tid >> 6;
  const int wm = (wave >> 1) * 64;
  const int wn = (wave & 1) * 64;
  const int l15  = lane & 15;
  const int quad = lane >> 4;

  __shared__ u16 sA[3][128 * 32];
  __shared__ u16 sB[3][128 * 32];

  const int gr  = lane >> 2;
  const int gsw = (((lane & 3) ^ ((lane >> 3) & 3))) * 8;
  const u16* ag = hin + ((size_t)(e * TT + t0) + wave * 32 + gr) * HH + gsw;
  const u16* bg = w2b + ((size_t)(e * DD + d0) + wave * 32 + gr) * HH + gsw;

  const int rsw = (quad ^ ((l15 >> 1) & 3)) * 8;

  f32x4 acc[4][4];
  #pragma unroll
  for (int i = 0; i < 4; ++i)
    #pragma unroll
    for (int j = 0; j < 4; ++j) acc[i][j] = (f32x4)0.f;

  auto stage = [&](int buf, int ko) {
    const size_t koff = (size_t)ko * 32;
    #pragma unroll
    for (int i = 0; i < 2; ++i) {
      __builtin_amdgcn_global_load_lds(
          (const AS1 uint32_t*)(ag + (size_t)(i * 16) * HH + koff),
          (AS3 uint32_t*)&sA[buf][(wave * 32 + i * 16) * 32], 16, 0, 0);
      __builtin_amdgcn_global_load_lds(
          (const AS1 uint32_t*)(bg + (size_t)(i * 16) * HH + koff),
          (AS3 uint32_t*)&sB[buf][(wave * 32 + i * 16) * 32], 16, 0, 0);
    }
  };

  const int NT = HH / 32;   // 128
  stage(0, 0);
  stage(1, 1);

  int cur = 0;
  for (int t = 0; t < NT; ++t) {
    __builtin_amdgcn_sched_barrier(0);
    asm volatile("s_waitcnt vmcnt(4)" ::: "memory");
    __builtin_amdgcn_s_barrier();
    __builtin_amdgcn_sched_barrier(0);

    int nslot = cur + 2; if (nslot >= 3) nslot -= 3;
    stage(nslot, (t + 2) & (NT - 1));
    __builtin_amdgcn_sched_barrier(0);

    s16x8 af[4];
    #pragma unroll
    for (int im = 0; im < 4; ++im)
      af[im] = *(const s16x8*)&sA[cur][(wm + im * 16 + l15) * 32 + rsw];
    #pragma unroll
    for (int jn = 0; jn < 4; ++jn) {
      s16x8 bf = *(const s16x8*)&sB[cur][(wn + jn * 16 + l15) * 32 + rsw];
      #pragma unroll
      for (int im = 0; im < 4; ++im)
        acc[im][jn] = __builtin_amdgcn_mfma_f32_16x16x32_bf16(af[im], bf, acc[im][jn], 0, 0, 0);
    }
    ++cur; if (cur >= 3) cur -= 3;
  }
  asm volatile("s_waitcnt vmcnt(0)" ::: "memory");

  #pragma unroll
  for (int im = 0; im < 4; ++im)
    #pragma unroll
    for (int jn = 0; jn < 4; ++jn)
      #pragma unroll
      for (int r = 0; r < 4; ++r) {
        int row = wm + im * 16 + quad * 4 + r;
        int col = wn + jn * 16 + l15;
        out[(size_t)(e * TT + t0 + row) * DD + d0 + col] = acc[im][jn][r];
      }
}

// ---------------------------------------------------------------------------
// Launch. Workspace layout (fast path, 480 MiB):
//   [0,64M)    h bf16      [64M,96M)   xb bf16
//   [96M,224M) w1t bf16    [224M,352M) w3b bf16   [352M,480M) w2b bf16
// ---------------------------------------------------------------------------
extern "C" void kernel_launch(void* const* d_in, const int* in_sizes, int n_in,
                              void* d_out, int out_size, void* d_ws, size_t ws_size,
                              hipStream_t stream) {
  const float* x  = (const float*)d_in[0];
  const float* w1 = (const float*)d_in[1];
  const float* w2 = (const float*)d_in[2];
  const float* w3 = (const float*)d_in[3];
  float* out = (float*)d_out;

  const size_t SZ_H  = (size_t)EE * TT * HH * 2;
  const size_t SZ_XB = (size_t)EE * TT * DD * 2;
  const size_t SZ_W  = (size_t)EE * DD * HH * 2;
  const size_t OFF_XB  = SZ_H;
  const size_t OFF_W1T = OFF_XB + SZ_XB;
  const size_t OFF_W3B = OFF_W1T + SZ_W;
  const size_t OFF_W2B = OFF_W3B + SZ_W;
  const size_t WS_NEED = OFF_W2B + SZ_W;

  u16* hbuf = (u16*)d_ws;
  u16* xb   = (u16*)((char*)d_ws + OFF_XB);
  u16* w1t  = (u16*)((char*)d_ws + OFF_W1T);
  u16* w3b  = (u16*)((char*)d_ws + OFF_W3B);
  u16* w2b  = (u16*)((char*)d_ws + OFF_W2B);
  (void)ws_size; (void)WS_NEED;

  k_cvt<<<2048, 256, 0, stream>>>(x,  xb,  (int)((size_t)EE * TT * DD / 4));
  k_cvt<<<4096, 256, 0, stream>>>(w3, w3b, (int)((size_t)EE * DD * HH / 4));
  k_tr <<<dim3(HH / 64, DD / 64, EE), 256, 0, stream>>>(w1, w1t);

  dim3 g1(HH / 128, TT / 128, EE + 1);   // z==EE slab converts w2 concurrently
  k1_bf16<<<g1, dim3(256), 0, stream>>>(xb, w1t, w3b, hbuf, w2, w2b);

  dim3 g2(DD / 128, TT / 128, EE);
  k2_bf16<<<g2, dim3(256), 0, stream>>>(hbuf, w2b, out);
}

// Round 4
// 1355.391 us; speedup vs baseline: 1.0744x; 1.0325x over previous
//
#include <hip/hip_runtime.h>
#include <stdint.h>

#define EE 8
#define TT 1024
#define DD 2048
#define HH 4096

typedef unsigned short u16;
using s16x8 = __attribute__((ext_vector_type(8))) short;
using f32x4 = __attribute__((ext_vector_type(4))) float;

#define AS1 __attribute__((address_space(1)))
#define AS3 __attribute__((address_space(3)))

__device__ __forceinline__ uint32_t pack_bf16(float lo, float hi) {
#if __has_builtin(__builtin_amdgcn_cvt_pk_bf16_f32)
  typedef __bf16 bf16x2 __attribute__((ext_vector_type(2)));
  bf16x2 r = __builtin_amdgcn_cvt_pk_bf16_f32(lo, hi);
  return __builtin_bit_cast(uint32_t, r);
#else
  uint32_t ulo = __builtin_bit_cast(uint32_t, lo);
  uint32_t uhi = __builtin_bit_cast(uint32_t, hi);
  ulo += 0x7fffu + ((ulo >> 16) & 1u);
  uhi += 0x7fffu + ((uhi >> 16) & 1u);
  return (ulo >> 16) | (uhi & 0xffff0000u);
#endif
}

__device__ __forceinline__ u16 bf16_bits(float v) {
  uint32_t u = __builtin_bit_cast(uint32_t, v);
  u += 0x7fffu + ((u >> 16) & 1u);
  return (u16)(u >> 16);
}

// ---------------------------------------------------------------------------
// Prepass A: straight fp32 -> bf16 convert (x, w3). Grid-stride float4.
// ---------------------------------------------------------------------------
__global__ __launch_bounds__(256)
void k_cvt(const float* __restrict__ in, u16* __restrict__ out, int n4) {
  int i = blockIdx.x * blockDim.x + threadIdx.x;
  const int stride = gridDim.x * blockDim.x;
  for (; i < n4; i += stride) {
    float4 v = ((const float4*)in)[i];
    uint2 o;
    o.x = pack_bf16(v.x, v.y);
    o.y = pack_bf16(v.z, v.w);
    ((uint2*)out)[i] = o;
  }
}

// ---------------------------------------------------------------------------
// Prepass B: w1 [E][D][H] fp32 -> w1t [E][H][D] bf16 (transpose-convert).
// ---------------------------------------------------------------------------
__global__ __launch_bounds__(256)
void k_tr(const float* __restrict__ in, u16* __restrict__ out) {
  const int e  = blockIdx.z;
  const int d0 = blockIdx.y * 64;
  const int h0 = blockIdx.x * 64;
  __shared__ u16 sT[64][68];
  const int r  = threadIdx.x >> 4;         // 0..15
  const int c4 = (threadIdx.x & 15) * 4;   // 0,4,..,60
  #pragma unroll
  for (int p = 0; p < 4; ++p) {
    int d = r + p * 16;
    float4 v = *(const float4*)(in + ((size_t)e * DD + d0 + d) * HH + h0 + c4);
    uint2 o;
    o.x = pack_bf16(v.x, v.y);
    o.y = pack_bf16(v.z, v.w);
    *(uint2*)&sT[d][c4] = o;
  }
  __syncthreads();
  #pragma unroll
  for (int p = 0; p < 4; ++p) {
    int h = r + p * 16;
    uint2 o;
    o.x = (uint32_t)sT[c4 + 0][h] | ((uint32_t)sT[c4 + 1][h] << 16);
    o.y = (uint32_t)sT[c4 + 2][h] | ((uint32_t)sT[c4 + 3][h] << 16);
    *(uint2*)(out + ((size_t)e * HH + h0 + h) * DD + d0 + c4) = o;
  }
}

// ---------------------------------------------------------------------------
// Kernel 1: h = silu(x@w1) * (x@w3^T), all-bf16 operands.
// 3-buffer counted-vmcnt pipeline, both-sides XOR swizzle (verified: 0 bank
// conflicts). XCD-aware block remap: each XCD owns one t-row per expert so
// its 512KB x-tile stays L2-resident. z==EE slab converts w2 fp32->bf16.
// ---------------------------------------------------------------------------
__global__ __launch_bounds__(256, 2)
void k1_bf16(const u16* __restrict__ xb, const u16* __restrict__ w1t,
             const u16* __restrict__ w3b, u16* __restrict__ hout,
             const float* __restrict__ w2, u16* __restrict__ w2b) {
  // ---- fused w2 conversion blocks (overlap with GEMM blocks) ----
  if (blockIdx.z == EE) {
    const int nb = gridDim.x * gridDim.y;
    const int bidx = blockIdx.y * gridDim.x + blockIdx.x;
    int i = bidx * blockDim.x + threadIdx.x;
    const int stride = nb * blockDim.x;
    const int n4 = (int)((size_t)EE * DD * HH / 4);
    for (; i < n4; i += stride) {
      float4 v = ((const float4*)w2)[i];
      uint2 o;
      o.x = pack_bf16(v.x, v.y);
      o.y = pack_bf16(v.z, v.w);
      ((uint2*)w2b)[i] = o;
    }
    return;
  }

  const int e  = blockIdx.z;
  // XCD swizzle: 256 blocks/slice, dispatch pos p -> XCD p%8 (round-robin).
  // Transpose remap: XCD k executes t-row k (all 32 h-blocks) -> x-tile L2-hot.
  const int p  = blockIdx.y * gridDim.x + blockIdx.x;   // gridDim.x == 32
  const int wg = (p & 7) * 32 + (p >> 3);
  const int t0 = (wg >> 5) * 128;
  const int h0 = (wg & 31) * 128;
  const int tid  = threadIdx.x;
  const int lane = tid & 63;
  const int wave = tid >> 6;
  const int wm = (wave >> 1) * 64;
  const int wn = (wave & 1) * 64;
  const int l15  = lane & 15;
  const int quad = lane >> 4;

  __shared__ u16 sX [3][128 * 32];
  __shared__ u16 sW1[3][128 * 32];
  __shared__ u16 sW3[3][128 * 32];

  // glds: dest = wave-uniform base + lane*16B -> (row = lane>>2, slot = lane&3).
  // Source pre-swizzled: chunk = (lane&3) ^ ((lane>>3)&3)
  const int gr  = lane >> 2;
  const int gsw = (((lane & 3) ^ ((lane >> 3) & 3))) * 8;  // u16 col
  const u16* xg  = xb  + ((size_t)(e * TT + t0) + wave * 32 + gr) * DD + gsw;
  const u16* w1g = w1t + ((size_t)(e * HH + h0) + wave * 32 + gr) * DD + gsw;
  const u16* w3g = w3b + ((size_t)(e * HH + h0) + wave * 32 + gr) * DD + gsw;

  // read-side swizzle: slot' = quad ^ ((l15>>1)&3), per-lane constant
  const int rsw = (quad ^ ((l15 >> 1) & 3)) * 8;

  f32x4 acc1[4][4], acc3[4][4];
  #pragma unroll
  for (int i = 0; i < 4; ++i)
    #pragma unroll
    for (int j = 0; j < 4; ++j) { acc1[i][j] = (f32x4)0.f; acc3[i][j] = (f32x4)0.f; }

  auto stage = [&](int buf, int ko) {
    const size_t koff = (size_t)ko * 32;
    #pragma unroll
    for (int i = 0; i < 2; ++i) {
      __builtin_amdgcn_global_load_lds(
          (const AS1 uint32_t*)(xg + (size_t)(i * 16) * DD + koff),
          (AS3 uint32_t*)&sX[buf][(wave * 32 + i * 16) * 32], 16, 0, 0);
      __builtin_amdgcn_global_load_lds(
          (const AS1 uint32_t*)(w1g + (size_t)(i * 16) * DD + koff),
          (AS3 uint32_t*)&sW1[buf][(wave * 32 + i * 16) * 32], 16, 0, 0);
      __builtin_amdgcn_global_load_lds(
          (const AS1 uint32_t*)(w3g + (size_t)(i * 16) * DD + koff),
          (AS3 uint32_t*)&sW3[buf][(wave * 32 + i * 16) * 32], 16, 0, 0);
    }
  };

  const int NT = DD / 32;   // 64
  stage(0, 0);
  stage(1, 1);

  int cur = 0;
  for (int t = 0; t < NT; ++t) {
    __builtin_amdgcn_sched_barrier(0);
    asm volatile("s_waitcnt vmcnt(6)" ::: "memory");
    __builtin_amdgcn_s_barrier();
    __builtin_amdgcn_sched_barrier(0);

    int nslot = cur + 2; if (nslot >= 3) nslot -= 3;
    stage(nslot, (t + 2) & (NT - 1));   // dummy re-stage at tail keeps vmcnt exact
    __builtin_amdgcn_sched_barrier(0);

    s16x8 af[4];
    #pragma unroll
    for (int im = 0; im < 4; ++im)
      af[im] = *(const s16x8*)&sX[cur][(wm + im * 16 + l15) * 32 + rsw];
    #pragma unroll
    for (int jn = 0; jn < 4; ++jn) {
      s16x8 b1 = *(const s16x8*)&sW1[cur][(wn + jn * 16 + l15) * 32 + rsw];
      s16x8 b3 = *(const s16x8*)&sW3[cur][(wn + jn * 16 + l15) * 32 + rsw];
      #pragma unroll
      for (int im = 0; im < 4; ++im) {
        acc1[im][jn] = __builtin_amdgcn_mfma_f32_16x16x32_bf16(af[im], b1, acc1[im][jn], 0, 0, 0);
        acc3[im][jn] = __builtin_amdgcn_mfma_f32_16x16x32_bf16(af[im], b3, acc3[im][jn], 0, 0, 0);
      }
    }
    ++cur; if (cur >= 3) cur -= 3;
  }
  asm volatile("s_waitcnt vmcnt(0)" ::: "memory");

  #pragma unroll
  for (int im = 0; im < 4; ++im)
    #pragma unroll
    for (int jn = 0; jn < 4; ++jn)
      #pragma unroll
      for (int r = 0; r < 4; ++r) {
        int row = wm + im * 16 + quad * 4 + r;
        int col = wn + jn * 16 + l15;
        float a = acc1[im][jn][r];
        float g = acc3[im][jn][r];
        float s = 1.0f / (1.0f + __expf(-a));
        hout[(size_t)(e * TT + t0 + row) * HH + h0 + col] = bf16_bits(a * s * g);
      }
}

// ---------------------------------------------------------------------------
// Kernel 2: out = h @ w2^T.  NEW geometry: BM=128(t) x BN=256(d), 4 waves
// 1Mx4N, wave tile 128x64 -> 32 MFMA per 12 ds_reads per K-step (ratio 2.67,
// was 2.0) and half the blocks (512) -> half the per-CU barrier-steps.
// 3-buffer counted vmcnt(6) + both-sides swizzle. Natural x->XCD pinning
// makes each XCD's 2MB w2b slab L2-resident.
// ---------------------------------------------------------------------------
__global__ __launch_bounds__(256, 2)
void k2_bf16(const u16* __restrict__ hin, const u16* __restrict__ w2b,
             float* __restrict__ out) {
  const int e  = blockIdx.z;
  const int t0 = blockIdx.y * 128;
  const int d0 = blockIdx.x * 256;
  const int tid  = threadIdx.x;
  const int lane = tid & 63;
  const int wave = tid >> 6;        // 0..3
  const int wn   = wave * 64;       // d-col slab of this wave
  const int l15  = lane & 15;
  const int quad = lane >> 4;

  __shared__ u16 sA[3][128 * 32];   // h tile   (8KB/buf)
  __shared__ u16 sB[3][256 * 32];   // w2 tile (16KB/buf)

  const int gr  = lane >> 2;
  const int gsw = (((lane & 3) ^ ((lane >> 3) & 3))) * 8;
  const u16* ag = hin + ((size_t)(e * TT + t0) + wave * 16 + gr) * HH + gsw;
  const u16* bg = w2b + ((size_t)(e * DD + d0) + wave * 16 + gr) * HH + gsw;

  const int rsw = (quad ^ ((l15 >> 1) & 3)) * 8;

  f32x4 acc[8][4];
  #pragma unroll
  for (int i = 0; i < 8; ++i)
    #pragma unroll
    for (int j = 0; j < 4; ++j) acc[i][j] = (f32x4)0.f;

  auto stage = [&](int buf, int ko) {
    const size_t koff = (size_t)ko * 32;
    #pragma unroll
    for (int i = 0; i < 2; ++i)   // A: 128 rows in 2 calls (64 rows each)
      __builtin_amdgcn_global_load_lds(
          (const AS1 uint32_t*)(ag + (size_t)(i * 64) * HH + koff),
          (AS3 uint32_t*)&sA[buf][(i * 64 + wave * 16) * 32], 16, 0, 0);
    #pragma unroll
    for (int j = 0; j < 4; ++j)   // B: 256 rows in 4 calls
      __builtin_amdgcn_global_load_lds(
          (const AS1 uint32_t*)(bg + (size_t)(j * 64) * HH + koff),
          (AS3 uint32_t*)&sB[buf][(j * 64 + wave * 16) * 32], 16, 0, 0);
  };

  const int NT = HH / 32;   // 128
  stage(0, 0);
  stage(1, 1);

  int cur = 0;
  for (int t = 0; t < NT; ++t) {
    __builtin_amdgcn_sched_barrier(0);
    asm volatile("s_waitcnt vmcnt(6)" ::: "memory");
    __builtin_amdgcn_s_barrier();
    __builtin_amdgcn_sched_barrier(0);

    int nslot = cur + 2; if (nslot >= 3) nslot -= 3;
    stage(nslot, (t + 2) & (NT - 1));
    __builtin_amdgcn_sched_barrier(0);

    s16x8 af[8];
    #pragma unroll
    for (int im = 0; im < 8; ++im)
      af[im] = *(const s16x8*)&sA[cur][(im * 16 + l15) * 32 + rsw];
    #pragma unroll
    for (int jn = 0; jn < 4; ++jn) {
      s16x8 bf = *(const s16x8*)&sB[cur][(wn + jn * 16 + l15) * 32 + rsw];
      #pragma unroll
      for (int im = 0; im < 8; ++im)
        acc[im][jn] = __builtin_amdgcn_mfma_f32_16x16x32_bf16(af[im], bf, acc[im][jn], 0, 0, 0);
    }
    ++cur; if (cur >= 3) cur -= 3;
  }
  asm volatile("s_waitcnt vmcnt(0)" ::: "memory");

  #pragma unroll
  for (int im = 0; im < 8; ++im)
    #pragma unroll
    for (int jn = 0; jn < 4; ++jn)
      #pragma unroll
      for (int r = 0; r < 4; ++r) {
        int row = im * 16 + quad * 4 + r;
        int col = wn + jn * 16 + l15;
        out[(size_t)(e * TT + t0 + row) * DD + d0 + col] = acc[im][jn][r];
      }
}

// ---------------------------------------------------------------------------
// Launch. Workspace layout (480 MiB):
//   [0,64M)    h bf16      [64M,96M)   xb bf16
//   [96M,224M) w1t bf16    [224M,352M) w3b bf16   [352M,480M) w2b bf16
// ---------------------------------------------------------------------------
extern "C" void kernel_launch(void* const* d_in, const int* in_sizes, int n_in,
                              void* d_out, int out_size, void* d_ws, size_t ws_size,
                              hipStream_t stream) {
  const float* x  = (const float*)d_in[0];
  const float* w1 = (const float*)d_in[1];
  const float* w2 = (const float*)d_in[2];
  const float* w3 = (const float*)d_in[3];
  float* out = (float*)d_out;

  const size_t SZ_H  = (size_t)EE * TT * HH * 2;
  const size_t SZ_XB = (size_t)EE * TT * DD * 2;
  const size_t SZ_W  = (size_t)EE * DD * HH * 2;
  const size_t OFF_XB  = SZ_H;
  const size_t OFF_W1T = OFF_XB + SZ_XB;
  const size_t OFF_W3B = OFF_W1T + SZ_W;
  const size_t OFF_W2B = OFF_W3B + SZ_W;

  u16* hbuf = (u16*)d_ws;
  u16* xb   = (u16*)((char*)d_ws + OFF_XB);
  u16* w1t  = (u16*)((char*)d_ws + OFF_W1T);
  u16* w3b  = (u16*)((char*)d_ws + OFF_W3B);
  u16* w2b  = (u16*)((char*)d_ws + OFF_W2B);
  (void)ws_size;

  k_cvt<<<2048, 256, 0, stream>>>(x,  xb,  (int)((size_t)EE * TT * DD / 4));
  k_cvt<<<4096, 256, 0, stream>>>(w3, w3b, (int)((size_t)EE * DD * HH / 4));
  k_tr <<<dim3(HH / 64, DD / 64, EE), 256, 0, stream>>>(w1, w1t);

  dim3 g1(HH / 128, TT / 128, EE + 1);   // z==EE slab converts w2 concurrently
  k1_bf16<<<g1, dim3(256), 0, stream>>>(xb, w1t, w3b, hbuf, w2, w2b);

  dim3 g2(DD / 256, TT / 128, EE);
  k2_bf16<<<g2, dim3(256), 0, stream>>>(hbuf, w2b, out);
}